// Round 16
// baseline (37.912 us; speedup 1.0000x reference)
//
#include <hip/hip_runtime.h>
#include <hip/hip_bf16.h>

// Quanv1D: out[i] = bias[i] + sum_d s_i(d) |(W' m_p)_d|^2
// R16 = R15 (wave-register prep; fp16 single-term GEMM, M=128/16-wave,
// frag-order A, fused angle window) + s_setprio(1) around the MFMA
// clusters (phase 2 GEMM, phase 4 sign-GEMM). T5 regime: 2 independent
// blocks/CU at different phases => MFMA-phase wave preempts the other
// block's staging waves. No arithmetic change.
// Register budget: 1024-thr block => <=128 unified regs/wave; acc 64 +
// ~60 arch at the edge -- no reg prefetch. NEVER tight VGPR caps
// ((256,4)-class) -- silent miscompile (R3/R4/R5 vs R7).

#define TOTAL_PATCHES 65480
#define LOUT 8185
#define LBATCH 8192
#define NX 65536

typedef _Float16 f16x8 __attribute__((ext_vector_type(8)));
typedef float f32x4 __attribute__((ext_vector_type(4)));

static __device__ __forceinline__ unsigned short f2h_bits(float f) {
  union { _Float16 h; unsigned short u; } v;
  v.h = (_Float16)f;
  return v.u;
}

// ---------------- Kernel 1: W'-build, wave-register version --------------
// Block k (256 blocks x 64 threads): evolve |k> through 2x(8 Rot + 8 CNOT).
// Lane holds state amps for d = lane*4 + s, s=0..3.
// Output layout: off = (((k>>5)*32 + (n>>4))*64 + ((k>>3)&3)*16
//                       + (n&15))*8 + (k&7);  n<256:Re, n>=256:Im.
__global__ __launch_bounds__(64) void prep_all(const float* __restrict__ w,
                                               unsigned short* __restrict__ wf16) {
  const int k = blockIdx.x;
  const int lane = threadIdx.x;
  float re[4], im[4];
#pragma unroll
  for (int s = 0; s < 4; ++s) {
    re[s] = (lane * 4 + s == k) ? 1.f : 0.f;
    im[s] = 0.f;
  }

#pragma unroll
  for (int l = 0; l < 2; ++l) {
    // ---- 8 Rot gates ----
#pragma unroll
    for (int wi = 0; wi < 8; ++wi) {
      float phi = w[(l * 8 + wi) * 3 + 0];
      float th  = w[(l * 8 + wi) * 3 + 1];
      float om  = w[(l * 8 + wi) * 3 + 2];
      float ch = cosf(0.5f * th), sh = sinf(0.5f * th);
      float aa = 0.5f * (phi + om), bb = 0.5f * (phi - om);
      float ca = cosf(aa), sa = sinf(aa), cb = cosf(bb), sb = sinf(bb);
      float m00r = ch * ca, m00i = -ch * sa;
      float m01r = -sh * cb, m01i = -sh * sb;
      float m10r = sh * cb,  m10i = -sh * sb;
      float m11r = ch * ca,  m11i = ch * sa;
      const int p = 7 - wi;
      float or_[4], oi_[4];
#pragma unroll
      for (int s = 0; s < 4; ++s) { or_[s] = re[s]; oi_[s] = im[s]; }
#pragma unroll
      for (int s = 0; s < 4; ++s) {
        float pr_, pi_;
        if (p >= 2) {
          pr_ = __shfl_xor(or_[s], 1 << (p - 2), 64);
          pi_ = __shfl_xor(oi_[s], 1 << (p - 2), 64);
        } else {
          pr_ = or_[s ^ (1 << p)];
          pi_ = oi_[s ^ (1 << p)];
        }
        int bit = ((lane * 4 + s) >> p) & 1;
        float cAr = bit ? m11r : m00r, cAi = bit ? m11i : m00i;
        float cBr = bit ? m10r : m01r, cBi = bit ? m10i : m01i;
        re[s] = cAr * or_[s] - cAi * oi_[s] + cBr * pr_ - cBi * pi_;
        im[s] = cAr * oi_[s] + cAi * or_[s] + cBr * pi_ + cBi * pr_;
      }
    }
    // ---- 8 CNOTs: control c=wi, target t=(wi+r)&7, r=l+1 ----
    const int r = l + 1;
#pragma unroll
    for (int wi = 0; wi < 8; ++wi) {
      const int pc = 7 - wi;
      const int pt = 7 - ((wi + r) & 7);
      float or_[4], oi_[4];
#pragma unroll
      for (int s = 0; s < 4; ++s) { or_[s] = re[s]; oi_[s] = im[s]; }
#pragma unroll
      for (int s = 0; s < 4; ++s) {
        int d = lane * 4 + s;
        int ctrl = (d >> pc) & 1;
        if (pt >= 2) {
          int srcl = lane ^ (ctrl << (pt - 2));
          re[s] = __shfl(or_[s], srcl, 64);
          im[s] = __shfl(oi_[s], srcl, 64);
        } else {
          float fr = or_[s ^ (1 << pt)], fi = oi_[s ^ (1 << pt)];
          re[s] = ctrl ? fr : or_[s];
          im[s] = ctrl ? fi : oi_[s];
        }
      }
    }
  }

  // ---- phase (-i)^popc(k) + store ----
  const int pop = __popc(k) & 3;
#pragma unroll
  for (int s = 0; s < 4; ++s) {
    int d = lane * 4 + s;
    float vr = re[s], vi = im[s];
    float pr, qi;
    if (pop == 0)      { pr =  vr; qi =  vi; }
    else if (pop == 1) { pr =  vi; qi = -vr; }
    else if (pop == 2) { pr = -vr; qi = -vi; }
    else               { pr = -vi; qi =  vr; }
    int offR = (((k >> 5) * 32 + (d >> 4)) * 64 + ((k >> 3) & 3) * 16 + (d & 15)) * 8 + (k & 7);
    int n2 = d + 256;
    int offI = (((k >> 5) * 32 + (n2 >> 4)) * 64 + ((k >> 3) & 3) * 16 + (n2 & 15)) * 8 + (k & 7);
    wf16[offR] = f2h_bits(pr);
    wf16[offI] = f2h_bits(qi);
  }
}

// ---------------- Kernel 2: angles + m-gen + fp16 GEMM + epilogue --------
__global__ __launch_bounds__(1024, 1) void quanv_main(
    const float* __restrict__ x,
    const f16x8* __restrict__ wf, const float* __restrict__ bias,
    float* __restrict__ out) {
  __shared__ __align__(16) unsigned short R0[128 * 264];  // A-frag (64KB used) / probs [128][264]
  __shared__ float esm[1024];
  __shared__ float2 cssn2[144];
  const int tid = threadIdx.x;
  const int lane = tid & 63;
  const int wave = tid >> 6;
  const int pbase = blockIdx.x * 128;

  // --- phase 0: per-block cos/sin window (<=142 contiguous x elements) ---
  const int b0 = pbase / LOUT;
  const int base0 = b0 * LBATCH + (pbase - b0 * LOUT);
  if (tid < 144) {
    int g = base0 + tid;
    if (g > NX - 1) g = NX - 1;
    float t = tanhf(x[g]);
    float s, c;
    __sincosf(1.57079632679489662f * t, &s, &c);
    cssn2[tid] = make_float2(c, s);
  }
  __syncthreads();

  // --- phase 1: m-tile [128 x 256] fp16, FRAGMENT order, single pass ---
  {
    int pl = tid & 31;
    int q = (tid >> 5) & 7;
    int s = tid >> 8;
    int patch = pbase + s * 32 + pl;
    if (patch > TOTAL_PATCHES - 1) patch = TOTAL_PATCHES - 1;
    int b = patch / LOUT;
    int off0 = b * LBATCH + (patch - b * LOUT) - base0;   // 0..141
    float fc[8], fs[8];
#pragma unroll
    for (int wq = 0; wq < 8; ++wq) {
      float2 v = cssn2[off0 + wq];
      fc[wq] = v.x; fs[wq] = v.y;
    }
    float arr[32];
    arr[0] = ((q & 4) ? fs[0] : fc[0]) * ((q & 2) ? fs[1] : fc[1]) * ((q & 1) ? fs[2] : fc[2]);
#pragma unroll
    for (int lev = 0; lev < 5; ++lev) {
      int wq = 7 - lev;
      int sz = 1 << lev;
#pragma unroll
      for (int j = 0; j < 32; ++j) {
        if (j < sz) {
          float a = arr[j];
          arr[sz + j] = a * fs[wq];
          arr[j] = a * fc[wq];
        }
      }
    }
    int mtg = s * 2 + (pl >> 4);                    // 0..7
    int fragbase = (q * 8 + mtg) * 64 + (pl & 15);
#pragma unroll
    for (int khalf = 0; khalf < 4; ++khalf) {
      f16x8 vH;
#pragma unroll
      for (int jj = 0; jj < 8; ++jj) vH[jj] = (_Float16)arr[khalf * 8 + jj];
      *(f16x8*)&R0[(fragbase + khalf * 16) * 8] = vH;
    }
  }
  __syncthreads();

  // --- phase 2: fp16 GEMM; wave owns nt=wave (Re) + nt=16+wave (Im) ---
  f32x4 acc[8][2];
#pragma unroll
  for (int i = 0; i < 8; ++i)
#pragma unroll
    for (int j = 0; j < 2; ++j) acc[i][j] = (f32x4){0.f, 0.f, 0.f, 0.f};

#pragma unroll
  for (int kc = 0; kc < 8; ++kc) {
    f16x8 af[8];
#pragma unroll
    for (int mt = 0; mt < 8; ++mt)
      af[mt] = *(const f16x8*)&R0[((kc * 8 + mt) * 64 + lane) * 8];
#pragma unroll
    for (int t2 = 0; t2 < 2; ++t2) {
      int nt = (t2 == 0) ? wave : (16 + wave);
      f16x8 b = wf[(kc * 32 + nt) * 64 + lane];
      __builtin_amdgcn_s_setprio(1);
#pragma unroll
      for (int mt = 0; mt < 8; ++mt)
        acc[mt][t2] = __builtin_amdgcn_mfma_f32_16x16x32_f16(af[mt], b, acc[mt][t2], 0, 0, 0);
      __builtin_amdgcn_s_setprio(0);
    }
  }

  __syncthreads();
  // --- phase 3: probs p = re^2+im^2, single fp16 -> [128][264] (alias) ---
#pragma unroll
  for (int mt = 0; mt < 8; ++mt)
#pragma unroll
    for (int r = 0; r < 4; ++r) {
      float vr = acc[mt][0][r], vi = acc[mt][1][r];
      float p = vr * vr + vi * vi;
      int patch_l = mt * 16 + (lane >> 4) * 4 + r;
      int d = wave * 16 + (lane & 15);
      R0[patch_l * 264 + d] = f2h_bits(p);
    }
  __syncthreads();

  // --- phase 4: sign-GEMM (waves 0..7, 16 patches each) ---
  if (wave < 8) {
    f32x4 e4 = {0.f, 0.f, 0.f, 0.f};
    int io = lane & 15;
    int plr = wave * 16 + (lane & 15);
    int hi4 = lane >> 4;
    __builtin_amdgcn_s_setprio(1);
#pragma unroll
    for (int kc2 = 0; kc2 < 8; ++kc2) {
      int k0 = kc2 * 32 + hi4 * 8;
      f16x8 aH = *(const f16x8*)&R0[plr * 264 + k0];
      f16x8 b2;
#pragma unroll
      for (int bb = 0; bb < 8; ++bb) {
        _Float16 sv = (_Float16)0.f;
        if (io < 8) sv = (((k0 + bb) >> (7 - io)) & 1) ? (_Float16)(-1.f) : (_Float16)(1.f);
        b2[bb] = sv;
      }
      e4 = __builtin_amdgcn_mfma_f32_16x16x32_f16(aH, b2, e4, 0, 0, 0);
    }
    __builtin_amdgcn_s_setprio(0);
    if (io < 8) {
      float bv = bias[io];
#pragma unroll
      for (int r = 0; r < 4; ++r)
        esm[io * 128 + (wave * 16 + hi4 * 4 + r)] = e4[r] + bv;
    }
  }
  __syncthreads();

  // --- phase 5: coalesced transposed store out[b][i][l], single pass ---
  {
    int io2 = tid >> 7, pl2 = tid & 127;
    int patch = pbase + pl2;
    if (patch < TOTAL_PATCHES) {
      int b = patch / LOUT;
      int l = patch - b * LOUT;
      out[(b * 8 + io2) * LOUT + l] = esm[io2 * 128 + pl2];
    }
  }
}

extern "C" void kernel_launch(void* const* d_in, const int* in_sizes, int n_in,
                              void* d_out, int out_size, void* d_ws, size_t ws_size,
                              hipStream_t stream) {
  const float* x = (const float*)d_in[0];
  const float* w = (const float*)d_in[1];
  const float* bias = (const float*)d_in[2];
  float* out = (float*)d_out;
  char* ws = (char*)d_ws;
  unsigned short* wf16 = (unsigned short*)ws;           // 262144 B

  prep_all<<<256, 64, 0, stream>>>(w, wf16);
  quanv_main<<<512, 1024, 0, stream>>>(x, (const f16x8*)wf16, bias, out);
}

// Round 17
// 36.330 us; speedup vs baseline: 1.0435x; 1.0435x over previous
//
#include <hip/hip_runtime.h>
#include <hip/hip_bf16.h>

// Quanv1D: out[i] = bias[i] + sum_d s_i(d) |(W' m_p)_d|^2
// R17 = byte-exact revert to R15 (best verified: 36.5 us total).
// R16's s_setprio experiment regressed (-1.4 us): with 2 barrier-synced
// 16-wave blocks/CU there is no per-phase wave role diversity within the
// arbitration scope -- m190's GEMM-null regime. Reverted.
// Structure: wave-register prep (no LDS/barriers) + fused quanv_main
// (fp16 single-term GEMM, M=128/16-wave, frag-order A, LDS angle window,
// aliased probs, sign-GEMM, transposed store).
// Register budget: 1024-thr block => <=128 unified regs/wave; acc 64 +
// ~60 arch at the edge -- no reg prefetch. NEVER tight VGPR caps
// ((256,4)-class) -- silent miscompile (R3/R4/R5 vs R7).

#define TOTAL_PATCHES 65480
#define LOUT 8185
#define LBATCH 8192
#define NX 65536

typedef _Float16 f16x8 __attribute__((ext_vector_type(8)));
typedef float f32x4 __attribute__((ext_vector_type(4)));

static __device__ __forceinline__ unsigned short f2h_bits(float f) {
  union { _Float16 h; unsigned short u; } v;
  v.h = (_Float16)f;
  return v.u;
}

// ---------------- Kernel 1: W'-build, wave-register version --------------
// Block k (256 blocks x 64 threads): evolve |k> through 2x(8 Rot + 8 CNOT).
// Lane holds state amps for d = lane*4 + s, s=0..3.
// Output layout: off = (((k>>5)*32 + (n>>4))*64 + ((k>>3)&3)*16
//                       + (n&15))*8 + (k&7);  n<256:Re, n>=256:Im.
__global__ __launch_bounds__(64) void prep_all(const float* __restrict__ w,
                                               unsigned short* __restrict__ wf16) {
  const int k = blockIdx.x;
  const int lane = threadIdx.x;
  float re[4], im[4];
#pragma unroll
  for (int s = 0; s < 4; ++s) {
    re[s] = (lane * 4 + s == k) ? 1.f : 0.f;
    im[s] = 0.f;
  }

#pragma unroll
  for (int l = 0; l < 2; ++l) {
    // ---- 8 Rot gates ----
#pragma unroll
    for (int wi = 0; wi < 8; ++wi) {
      float phi = w[(l * 8 + wi) * 3 + 0];
      float th  = w[(l * 8 + wi) * 3 + 1];
      float om  = w[(l * 8 + wi) * 3 + 2];
      float ch = cosf(0.5f * th), sh = sinf(0.5f * th);
      float aa = 0.5f * (phi + om), bb = 0.5f * (phi - om);
      float ca = cosf(aa), sa = sinf(aa), cb = cosf(bb), sb = sinf(bb);
      float m00r = ch * ca, m00i = -ch * sa;
      float m01r = -sh * cb, m01i = -sh * sb;
      float m10r = sh * cb,  m10i = -sh * sb;
      float m11r = ch * ca,  m11i = ch * sa;
      const int p = 7 - wi;
      float or_[4], oi_[4];
#pragma unroll
      for (int s = 0; s < 4; ++s) { or_[s] = re[s]; oi_[s] = im[s]; }
#pragma unroll
      for (int s = 0; s < 4; ++s) {
        float pr_, pi_;
        if (p >= 2) {
          pr_ = __shfl_xor(or_[s], 1 << (p - 2), 64);
          pi_ = __shfl_xor(oi_[s], 1 << (p - 2), 64);
        } else {
          pr_ = or_[s ^ (1 << p)];
          pi_ = oi_[s ^ (1 << p)];
        }
        int bit = ((lane * 4 + s) >> p) & 1;
        float cAr = bit ? m11r : m00r, cAi = bit ? m11i : m00i;
        float cBr = bit ? m10r : m01r, cBi = bit ? m10i : m01i;
        re[s] = cAr * or_[s] - cAi * oi_[s] + cBr * pr_ - cBi * pi_;
        im[s] = cAr * oi_[s] + cAi * or_[s] + cBr * pi_ + cBi * pr_;
      }
    }
    // ---- 8 CNOTs: control c=wi, target t=(wi+r)&7, r=l+1 ----
    const int r = l + 1;
#pragma unroll
    for (int wi = 0; wi < 8; ++wi) {
      const int pc = 7 - wi;
      const int pt = 7 - ((wi + r) & 7);
      float or_[4], oi_[4];
#pragma unroll
      for (int s = 0; s < 4; ++s) { or_[s] = re[s]; oi_[s] = im[s]; }
#pragma unroll
      for (int s = 0; s < 4; ++s) {
        int d = lane * 4 + s;
        int ctrl = (d >> pc) & 1;
        if (pt >= 2) {
          int srcl = lane ^ (ctrl << (pt - 2));
          re[s] = __shfl(or_[s], srcl, 64);
          im[s] = __shfl(oi_[s], srcl, 64);
        } else {
          float fr = or_[s ^ (1 << pt)], fi = oi_[s ^ (1 << pt)];
          re[s] = ctrl ? fr : or_[s];
          im[s] = ctrl ? fi : oi_[s];
        }
      }
    }
  }

  // ---- phase (-i)^popc(k) + store ----
  const int pop = __popc(k) & 3;
#pragma unroll
  for (int s = 0; s < 4; ++s) {
    int d = lane * 4 + s;
    float vr = re[s], vi = im[s];
    float pr, qi;
    if (pop == 0)      { pr =  vr; qi =  vi; }
    else if (pop == 1) { pr =  vi; qi = -vr; }
    else if (pop == 2) { pr = -vr; qi = -vi; }
    else               { pr = -vi; qi =  vr; }
    int offR = (((k >> 5) * 32 + (d >> 4)) * 64 + ((k >> 3) & 3) * 16 + (d & 15)) * 8 + (k & 7);
    int n2 = d + 256;
    int offI = (((k >> 5) * 32 + (n2 >> 4)) * 64 + ((k >> 3) & 3) * 16 + (n2 & 15)) * 8 + (k & 7);
    wf16[offR] = f2h_bits(pr);
    wf16[offI] = f2h_bits(qi);
  }
}

// ---------------- Kernel 2: angles + m-gen + fp16 GEMM + epilogue --------
__global__ __launch_bounds__(1024, 1) void quanv_main(
    const float* __restrict__ x,
    const f16x8* __restrict__ wf, const float* __restrict__ bias,
    float* __restrict__ out) {
  __shared__ __align__(16) unsigned short R0[128 * 264];  // A-frag (64KB used) / probs [128][264]
  __shared__ float esm[1024];
  __shared__ float2 cssn2[144];
  const int tid = threadIdx.x;
  const int lane = tid & 63;
  const int wave = tid >> 6;
  const int pbase = blockIdx.x * 128;

  // --- phase 0: per-block cos/sin window (<=142 contiguous x elements) ---
  const int b0 = pbase / LOUT;
  const int base0 = b0 * LBATCH + (pbase - b0 * LOUT);
  if (tid < 144) {
    int g = base0 + tid;
    if (g > NX - 1) g = NX - 1;
    float t = tanhf(x[g]);
    float s, c;
    __sincosf(1.57079632679489662f * t, &s, &c);
    cssn2[tid] = make_float2(c, s);
  }
  __syncthreads();

  // --- phase 1: m-tile [128 x 256] fp16, FRAGMENT order, single pass ---
  {
    int pl = tid & 31;
    int q = (tid >> 5) & 7;
    int s = tid >> 8;
    int patch = pbase + s * 32 + pl;
    if (patch > TOTAL_PATCHES - 1) patch = TOTAL_PATCHES - 1;
    int b = patch / LOUT;
    int off0 = b * LBATCH + (patch - b * LOUT) - base0;   // 0..141
    float fc[8], fs[8];
#pragma unroll
    for (int wq = 0; wq < 8; ++wq) {
      float2 v = cssn2[off0 + wq];
      fc[wq] = v.x; fs[wq] = v.y;
    }
    float arr[32];
    arr[0] = ((q & 4) ? fs[0] : fc[0]) * ((q & 2) ? fs[1] : fc[1]) * ((q & 1) ? fs[2] : fc[2]);
#pragma unroll
    for (int lev = 0; lev < 5; ++lev) {
      int wq = 7 - lev;
      int sz = 1 << lev;
#pragma unroll
      for (int j = 0; j < 32; ++j) {
        if (j < sz) {
          float a = arr[j];
          arr[sz + j] = a * fs[wq];
          arr[j] = a * fc[wq];
        }
      }
    }
    int mtg = s * 2 + (pl >> 4);                    // 0..7
    int fragbase = (q * 8 + mtg) * 64 + (pl & 15);
#pragma unroll
    for (int khalf = 0; khalf < 4; ++khalf) {
      f16x8 vH;
#pragma unroll
      for (int jj = 0; jj < 8; ++jj) vH[jj] = (_Float16)arr[khalf * 8 + jj];
      *(f16x8*)&R0[(fragbase + khalf * 16) * 8] = vH;
    }
  }
  __syncthreads();

  // --- phase 2: fp16 GEMM; wave owns nt=wave (Re) + nt=16+wave (Im) ---
  f32x4 acc[8][2];
#pragma unroll
  for (int i = 0; i < 8; ++i)
#pragma unroll
    for (int j = 0; j < 2; ++j) acc[i][j] = (f32x4){0.f, 0.f, 0.f, 0.f};

#pragma unroll
  for (int kc = 0; kc < 8; ++kc) {
    f16x8 af[8];
#pragma unroll
    for (int mt = 0; mt < 8; ++mt)
      af[mt] = *(const f16x8*)&R0[((kc * 8 + mt) * 64 + lane) * 8];
#pragma unroll
    for (int t2 = 0; t2 < 2; ++t2) {
      int nt = (t2 == 0) ? wave : (16 + wave);
      f16x8 b = wf[(kc * 32 + nt) * 64 + lane];
#pragma unroll
      for (int mt = 0; mt < 8; ++mt)
        acc[mt][t2] = __builtin_amdgcn_mfma_f32_16x16x32_f16(af[mt], b, acc[mt][t2], 0, 0, 0);
    }
  }

  __syncthreads();
  // --- phase 3: probs p = re^2+im^2, single fp16 -> [128][264] (alias) ---
#pragma unroll
  for (int mt = 0; mt < 8; ++mt)
#pragma unroll
    for (int r = 0; r < 4; ++r) {
      float vr = acc[mt][0][r], vi = acc[mt][1][r];
      float p = vr * vr + vi * vi;
      int patch_l = mt * 16 + (lane >> 4) * 4 + r;
      int d = wave * 16 + (lane & 15);
      R0[patch_l * 264 + d] = f2h_bits(p);
    }
  __syncthreads();

  // --- phase 4: sign-GEMM (waves 0..7, 16 patches each) ---
  if (wave < 8) {
    f32x4 e4 = {0.f, 0.f, 0.f, 0.f};
    int io = lane & 15;
    int plr = wave * 16 + (lane & 15);
    int hi4 = lane >> 4;
#pragma unroll
    for (int kc2 = 0; kc2 < 8; ++kc2) {
      int k0 = kc2 * 32 + hi4 * 8;
      f16x8 aH = *(const f16x8*)&R0[plr * 264 + k0];
      f16x8 b2;
#pragma unroll
      for (int bb = 0; bb < 8; ++bb) {
        _Float16 sv = (_Float16)0.f;
        if (io < 8) sv = (((k0 + bb) >> (7 - io)) & 1) ? (_Float16)(-1.f) : (_Float16)(1.f);
        b2[bb] = sv;
      }
      e4 = __builtin_amdgcn_mfma_f32_16x16x32_f16(aH, b2, e4, 0, 0, 0);
    }
    if (io < 8) {
      float bv = bias[io];
#pragma unroll
      for (int r = 0; r < 4; ++r)
        esm[io * 128 + (wave * 16 + hi4 * 4 + r)] = e4[r] + bv;
    }
  }
  __syncthreads();

  // --- phase 5: coalesced transposed store out[b][i][l], single pass ---
  {
    int io2 = tid >> 7, pl2 = tid & 127;
    int patch = pbase + pl2;
    if (patch < TOTAL_PATCHES) {
      int b = patch / LOUT;
      int l = patch - b * LOUT;
      out[(b * 8 + io2) * LOUT + l] = esm[io2 * 128 + pl2];
    }
  }
}

extern "C" void kernel_launch(void* const* d_in, const int* in_sizes, int n_in,
                              void* d_out, int out_size, void* d_ws, size_t ws_size,
                              hipStream_t stream) {
  const float* x = (const float*)d_in[0];
  const float* w = (const float*)d_in[1];
  const float* bias = (const float*)d_in[2];
  float* out = (float*)d_out;
  char* ws = (char*)d_ws;
  unsigned short* wf16 = (unsigned short*)ws;           // 262144 B

  prep_all<<<256, 64, 0, stream>>>(w, wf16);
  quanv_main<<<512, 1024, 0, stream>>>(x, (const f16x8*)wf16, bias, out);
}